// Round 17
// baseline (117.804 us; speedup 1.0000x reference)
//
#include <hip/hip_runtime.h>
#include <math.h>

#define DIM 64
#define HEADS 4
#define BB 8
#define QQ 128
#define VV 128
#define NN (BB*QQ)   // 1024

typedef float f2 __attribute__((ext_vector_type(2)));
typedef float f4 __attribute__((ext_vector_type(4)));

// ---- DPP helpers (VALU, no DS); CTRL is a compile-time template constant ----
template <int CTRL>
__device__ __forceinline__ float dppf(float x) {
    return __int_as_float(__builtin_amdgcn_update_dpp(
        0, __float_as_int(x), CTRL, 0xF, 0xF, true));
}
#define WSHR1 0x138  // wave_shr:1 : lane l <- l-1 (lane 0 -> 0)
#define WSHL1 0x130  // wave_shl:1 : lane l <- l+1 (lane 63 -> 0)

// K1: Av[h][row][j] = f32 (re,im) of sum_i values[row,i] * U[h, 64+i, j]
__global__ __launch_bounds__(256) void k_av(const float* __restrict__ values,
                                            const float* __restrict__ U_re,
                                            const float* __restrict__ U_im,
                                            f2* __restrict__ Av) {
    int tid = blockIdx.x * blockDim.x + threadIdx.x;
    int w = tid >> 6;            // 0..2047
    int j = tid & 63;
    int h = w >> 9;              // 0..3
    int r0 = (w & 511) << 1;     // first of 2 rows within head h
    const float* vrow = values + r0 * DIM;                     // wave-uniform
    const float* ur = U_re + (h * 2 * DIM + DIM) * DIM + j;    // bottom half
    const float* ui = U_im + (h * 2 * DIM + DIM) * DIM + j;
    f2 a0 = 0.f, a1 = 0.f;
    #pragma unroll 8
    for (int i = 0; i < DIM; ++i) {
        f2 u; u.x = ur[i * DIM]; u.y = ui[i * DIM];
        a0 += vrow[i] * u;                 // s_load scalars broadcast
        a1 += vrow[DIM + i] * u;
    }
    f2* out = Av + (h * 1024 + r0) * DIM + j;
    out[0] = a0; out[DIM] = a1;
}

// K2: 512 blocks = (b, q); 4 waves = 4 heads. NEW LANE MAP: lane l holds dims
// (2k, 2k+1), k = l&31, of chain c = l>>5 (c=0: row n0, c=1: row n1).
// Layer-1 is lane-LOCAL (no DPP); layer-2 needs one shl1 + one shr1 pair.
// Chain-seam contamination (lane 31<->32) is killed by endpoint coefs == 0.
// Both chains share one Av stream (same b) -> one dwordx4 per step.
__global__ __launch_bounds__(256) void k_rnn_dense(
        const float* __restrict__ queries,
        const float* __restrict__ U_re,
        const float* __restrict__ U_im,
        const float* __restrict__ bias,
        const float* __restrict__ theta1,
        const float* __restrict__ phi1,
        const float* __restrict__ theta2,
        const float* __restrict__ phi2,
        const float* __restrict__ omega,
        const float* __restrict__ Av,
        const float* __restrict__ W_dense,
        const float* __restrict__ b_dense,
        float* __restrict__ y) {
    int b = blockIdx.x >> 6;   // 0..7
    int q = blockIdx.x & 63;   // 0..63
    int t = threadIdx.x;
    int h = t >> 6;            // head = wave
    int l = t & 63;            // lane
    int k = l & 31;            // pair index: dims 2k, 2k+1
    int n0 = b * 128 + q;
    int n1 = n0 + 64;
    int myrow = (l < 32) ? n0 : n1;

    // ---- layer 1 (lane-local): a' = E1*(C1*a - S1*b); b' = S1*a + C1*b ----
    float th1 = theta1[h * 32 + k], ph1 = phi1[h * 32 + k];
    float C1 = cosf(th1), S1 = sinf(th1), nS1 = -S1;
    float E1r = cosf(ph1), E1i = sinf(ph1), nE1i = -E1i;

    // ---- layer 2: b-out (dim 2k+1) pairs with next lane's a; a-out (dim 2k)
    //      pairs with prev lane's b. Endpoints: k=31 b-out, k=0 a-out. ----
    float C2b, nS2b, e2r, e2i;
    if (k < 31) {
        float th2 = theta2[h * 31 + k], ph2 = phi2[h * 31 + k];
        C2b = cosf(th2); nS2b = -sinf(th2);
        e2r = cosf(ph2); e2i = sinf(ph2);
    } else { C2b = 1.f; nS2b = 0.f; e2r = 1.f; e2i = 0.f; }
    float C2a, SRa;
    if (k > 0) {
        float th2p = theta2[h * 31 + (k - 1)];
        C2a = cosf(th2p); SRa = sinf(th2p);
    } else { C2a = 1.f; SRa = 0.f; }

    // phases: PHa = e^{i*om[2k]}; PHb = e2 * e^{i*om[2k+1]}
    float oma = omega[h * 64 + 2 * k], omb = omega[h * 64 + 2 * k + 1];
    float PHar = cosf(oma), PHai = sinf(oma), nPHai = -PHai;
    float obr = cosf(omb), obi = sinf(omb);
    float PHbr = e2r * obr - e2i * obi;
    float PHbi = e2r * obi + e2i * obr;
    float nPHbi = -PHbi;
    float bja = bias[h * 64 + 2 * k], bjb = bias[h * 64 + 2 * k + 1];

    // ---- Aq for my row, dims 2k & 2k+1 ----
    const float* qp = queries + myrow * DIM;      // half-wave-uniform address
    const f2* urp = (const f2*)(U_re + (h * 2 * DIM) * DIM + 2 * k);
    const f2* uip = (const f2*)(U_im + (h * 2 * DIM) * DIM + 2 * k);
    float uqar = 0.f, uqai = 0.f, uqbr = 0.f, uqbi = 0.f;
    #pragma unroll 8
    for (int i = 0; i < DIM; ++i) {
        float qv = qp[i];
        f2 wr = urp[i * (DIM / 2)];
        f2 wi = uip[i * (DIM / 2)];
        uqar = fmaf(qv, wr.x, uqar); uqbr = fmaf(qv, wr.y, uqbr);
        uqai = fmaf(qv, wi.x, uqai); uqbi = fmaf(qv, wi.y, uqbi);
    }

    float ar = 0.f, ai = 0.f, br = 0.f, bi = 0.f;   // state dims 2k, 2k+1
    auto step = [&](f4 av) {
        float uvar = uqar + av.x, uvai = uqai + av.y;   // off-chain
        float uvbr = uqbr + av.z, uvbi = uqbi + av.w;
        // layer 1 (lane-local)
        float tar = C1 * ar; tar = fmaf(nS1, br, tar);
        float tai = C1 * ai; tai = fmaf(nS1, bi, tai);
        float Tar = fmaf(E1r, tar, nE1i * tai);
        float Tai = fmaf(E1r, tai, E1i * tar);
        float Tbr = fmaf(S1, ar, C1 * br);
        float Tbi = fmaf(S1, ai, C1 * bi);
        // layer 2 exchange (4 DPP for both chains; seam killed by coef=0)
        float Lar = dppf<WSHL1>(Tar), Lai = dppf<WSHL1>(Tai);
        float Rbr = dppf<WSHR1>(Tbr), Rbi = dppf<WSHR1>(Tbi);
        float bppr = C2b * Tbr; bppr = fmaf(nS2b, Lar, bppr);
        float bppi = C2b * Tbi; bppi = fmaf(nS2b, Lai, bppi);
        float appr = C2a * Tar; appr = fmaf(SRa, Rbr, appr);
        float appi = C2a * Tai; appi = fmaf(SRa, Rbi, appi);
        // phase + input
        float zar = fmaf(PHar, appr, fmaf(nPHai, appi, uvar));
        float zai = fmaf(PHar, appi, fmaf(PHai, appr, uvai));
        float zbr = fmaf(PHbr, bppr, fmaf(nPHbi, bppi, uvbr));
        float zbi = fmaf(PHbr, bppi, fmaf(PHbi, bppr, uvbi));
        // modrelu x2: sc = max(1 + bias*rsq(|z|^2+eps), 0)
        float q2a = fmaf(zar, zar, fmaf(zai, zai, 1e-10f));
        float rsa = __builtin_amdgcn_rsqf(q2a);
        float sca = fmaxf(fmaf(bja, rsa, 1.f), 0.f);
        ar = zar * sca; ai = zai * sca;
        float q2b = fmaf(zbr, zbr, fmaf(zbi, zbi, 1e-10f));
        float rsb = __builtin_amdgcn_rsqf(q2b);
        float scb = fmaxf(fmaf(bjb, rsb, 1.f), 0.f);
        br = zbr * scb; bi = zbi * scb;
    };

    // Av stream (shared by both chains): f4 index (h*1024 + b*128 + v)*32 + k
    const f4* p = (const f4*)Av + (h * 1024 + b * 128) * 32 + k;

    // batches of 4 steps, register double-buffered
    f4 buf[4], nxt[4];
    #pragma unroll
    for (int m = 0; m < 4; ++m) buf[m] = p[m * 32];

    for (int vb = 0; vb < VV; vb += 4) {
        const f4* pn = p + ((vb < VV - 4) ? 4 * 32 : 0);
        #pragma unroll
        for (int m = 0; m < 4; ++m) nxt[m] = pn[m * 32];
        p = pn;
        #pragma unroll
        for (int m = 0; m < 4; ++m) step(buf[m]);
        #pragma unroll
        for (int m = 0; m < 4; ++m) buf[m] = nxt[m];
    }

    // ---- fused dense for rows n0, n1 ----
    __shared__ float s_acc[2][HEADS * DIM];   // 2 x 256
    __shared__ float s_part[256];
    {
        int c = l >> 5;
        s_acc[c][h * 64 + 2 * k]     = ar;    // Re(h_a)
        s_acc[c][h * 64 + 2 * k + 1] = br;    // Re(h_b)
    }
    __syncthreads();

    {   // thread t: row r = t>>7, k-half hf = (t>>6)&1, col jj = t&63
        int r = t >> 7, hf = (t >> 6) & 1, jj = t & 63;
        const float* Wp = W_dense + (hf * 128) * DIM + jj;
        const float* ap = &s_acc[r][hf * 128];
        float part = 0.f;
        #pragma unroll 8
        for (int kk = 0; kk < 128; ++kk)
            part = fmaf(ap[kk], Wp[kk * DIM], part);  // ap broadcast, Wp coalesced
        s_part[t] = part;
    }
    __syncthreads();
    if (t < 128) {
        int r = t >> 6, jj = t & 63;
        y[(n0 + r * 64) * DIM + jj] =
            b_dense[jj] + s_part[r * 128 + jj] + s_part[r * 128 + 64 + jj];
    }
}

extern "C" void kernel_launch(void* const* d_in, const int* in_sizes, int n_in,
                              void* d_out, int out_size, void* d_ws, size_t ws_size,
                              hipStream_t stream) {
    const float* queries = (const float*)d_in[0];
    const float* values  = (const float*)d_in[1];
    const float* U_re    = (const float*)d_in[2];
    const float* U_im    = (const float*)d_in[3];
    const float* bias    = (const float*)d_in[4];
    const float* theta1  = (const float*)d_in[5];
    const float* phi1    = (const float*)d_in[6];
    const float* theta2  = (const float*)d_in[7];
    const float* phi2    = (const float*)d_in[8];
    const float* omega   = (const float*)d_in[9];
    const float* W_dense = (const float*)d_in[10];
    const float* b_dense = (const float*)d_in[11];
    float* y = (float*)d_out;

    f2* Av = (f2*)d_ws;   // [h][row][j] f2 = 2 MB

    k_av<<<512, 256, 0, stream>>>(values, U_re, U_im, Av);
    k_rnn_dense<<<512, 256, 0, stream>>>(queries, U_re, U_im, bias, theta1,
                                         phi1, theta2, phi2, omega, (const float*)Av,
                                         W_dense, b_dense, y);
}